// Round 1
// baseline (1347.908 us; speedup 1.0000x reference)
//
#include <hip/hip_runtime.h>
#include <hip/hip_fp16.h>

#define B_ 64
#define L_ 2048
#define D_ 256
#define TC 16
#define TP 32

typedef _Float16 half8 __attribute__((ext_vector_type(8)));
typedef _Float16 f16x2 __attribute__((ext_vector_type(2)));
typedef float f32x4 __attribute__((ext_vector_type(4)));

#define LOG2E 1.4426950408889634f
#define TWO_LOG2E 2.8853900817779268f

__device__ __forceinline__ float ex2(float x){ return __builtin_amdgcn_exp2f(x); }
__device__ __forceinline__ float rcp_(float x){ return __builtin_amdgcn_rcpf(x); }
__device__ __forceinline__ float sigm(float x){ return rcp_(1.f + ex2(-LOG2E*x)); }
__device__ __forceinline__ float tanh_(float x){ return 1.f - 2.f*rcp_(1.f + ex2(TWO_LOG2E*x)); }

#if __has_builtin(__builtin_amdgcn_fdot2)
__device__ __forceinline__ float fdot2_(f16x2 a, f16x2 b, float c){ return __builtin_amdgcn_fdot2(a,b,c,false); }
#else
__device__ __forceinline__ float fdot2_(f16x2 a, f16x2 b, float c){
  return fmaf((float)a[0], (float)b[0], fmaf((float)a[1], (float)b[1], c));
}
#endif

__device__ __forceinline__ void cvt8(uint4 v, float* w){
  const __half2* h = (const __half2*)&v;
#pragma unroll
  for (int i=0;i<4;i++){ float2 f = __half22float2(h[i]); w[2*i]=f.x; w[2*i+1]=f.y; }
}

// ---------------- K1: weight prep (fp16 casts, transposed Wk, parentT) ----------------
__global__ __launch_bounds__(256) void k_prep(
    const float* __restrict__ sf,
    const float* __restrict__ wk_c, const float* __restrict__ wk_p,
    const float* __restrict__ wih_c, const float* __restrict__ wih_p,
    const float* __restrict__ whh_c, const float* __restrict__ whh_p,
    __half* __restrict__ wkT, __half* __restrict__ wihH, __half* __restrict__ whhH,
    float* __restrict__ parentT)
{
  int idx = blockIdx.x*256 + threadIdx.x;
  if (idx < 131072) {
    int c = idx >> 8, d = idx & 255;
    int net = c >> 8, e = c & 255;
    const float* w = net ? wk_p : wk_c;
    wkT[idx] = __float2half(w[d*256 + e]);           // wkT[c][d] = Wk[d][e]
  } else if (idx < 131072 + 393216) {
    int i = idx - 131072;
    const float* w = (i < 196608) ? wih_c : wih_p;
    wihH[i] = __float2half(w[(i < 196608) ? i : i - 196608]);
  } else if (idx < 131072 + 786432) {
    int i = idx - 131072 - 393216;
    const float* w = (i < 196608) ? whh_c : whh_p;
    whhH[i] = __float2half(w[(i < 196608) ? i : i - 196608]);
  } else {
    int i = idx - 131072 - 786432;                   // < 16384
    int d = i >> 6, b = i & 63;
    parentT[i] = sf[((size_t)b*L_ + (L_-2))*D_ + d];
  }
}

// ---------------- K2: proj_k GEMM  pk[r][c] = sum_d emb[r][d]*WkT[c][d]  (fp16 MFMA) --
__global__ __launch_bounds__(256) void k_gemm(
    const float* __restrict__ sf, const __half* __restrict__ wkT, __half* __restrict__ pk)
{
  __shared__ __half As[128*40];
  __shared__ __half Bs[128*40];
  const int tid = threadIdx.x;
  const int row0 = blockIdx.x * 128;
  const int col0 = blockIdx.y * 128;
  const int lane = tid & 63, wave = tid >> 6;
  const int wm = wave & 1, wn = wave >> 1;
  const int qd = lane >> 4, mr = lane & 15;
  const int rl = tid >> 1, hf = tid & 1;

  f32x4 acc[4][4];
#pragma unroll
  for (int i=0;i<4;i++)
#pragma unroll
    for (int j=0;j<4;j++) acc[i][j] = (f32x4){0.f,0.f,0.f,0.f};

  for (int kc = 0; kc < 256; kc += 32) {
    const float* asrc = sf + ((size_t)(row0+rl))*256 + kc + hf*16;
    __half* adst = As + rl*40 + hf*16;
#pragma unroll
    for (int i=0;i<4;i++){
      float4 v = ((const float4*)asrc)[i];
      __half2 h01 = __floats2half2_rn(v.x, v.y);
      __half2 h23 = __floats2half2_rn(v.z, v.w);
      uint2 u; u.x = *(const unsigned*)&h01; u.y = *(const unsigned*)&h23;
      *(uint2*)(adst + i*4) = u;
    }
    const __half* bsrc = wkT + (size_t)(col0+rl)*256 + kc + hf*16;
    __half* bdst = Bs + rl*40 + hf*16;
    *(uint4*)bdst       = *(const uint4*)bsrc;
    *(uint4*)(bdst + 8) = *(const uint4*)(bsrc + 8);
    __syncthreads();

    half8 af[4], bf[4];
#pragma unroll
    for (int tm=0;tm<4;tm++) af[tm] = *(const half8*)(As + (wm*64 + tm*16 + mr)*40 + qd*8);
#pragma unroll
    for (int tn=0;tn<4;tn++) bf[tn] = *(const half8*)(Bs + (wn*64 + tn*16 + mr)*40 + qd*8);
#pragma unroll
    for (int tm=0;tm<4;tm++)
#pragma unroll
      for (int tn=0;tn<4;tn++)
        acc[tm][tn] = __builtin_amdgcn_mfma_f32_16x16x32_f16(af[tm], bf[tn], acc[tm][tn], 0,0,0);
    __syncthreads();
  }
#pragma unroll
  for (int tm=0;tm<4;tm++)
#pragma unroll
    for (int tn=0;tn<4;tn++){
      int c = col0 + wn*64 + tn*16 + mr;
#pragma unroll
      for (int rg=0; rg<4; rg++){
        int r = row0 + wm*64 + tm*16 + qd*4 + rg;
        pk[(size_t)r*512 + c] = __float2half(acc[tm][tn][rg]);
      }
    }
}

// ---------------- K3: M[net][b][k][e] = sum_d parent[b][d]*bilW[k][d][e]  (fp32) ------
__global__ __launch_bounds__(256) void k_M(
    const float* __restrict__ bw_c, const float* __restrict__ bw_p,
    const float* __restrict__ parentT, float* __restrict__ M)
{
  const int net = blockIdx.x >> 8;
  const int k = blockIdx.x & 255;
  const int e = threadIdx.x;
  const float* W = (net ? bw_p : bw_c) + (size_t)k*65536 + e;
  float acc[64];
#pragma unroll
  for (int b=0;b<64;b++) acc[b] = 0.f;
  for (int d=0; d<256; d++){
    float w = W[(size_t)d*256];
    const float* pr = parentT + d*64;   // uniform -> s_load
#pragma unroll
    for (int b=0;b<64;b++) acc[b] = fmaf(pr[b], w, acc[b]);
  }
  float* Mo = M + ((size_t)net*64*256 + k)*256 + e;
#pragma unroll
  for (int b=0;b<64;b++) Mo[(size_t)b*65536] = acc[b];
}

// ---------------- K4a: gi_all[b][t][j] = x_t[b] . Wih[j] + bih[j] (all t parallel) ----
template<int T>
__global__ __launch_bounds__(256) void k_gi(
    const float* __restrict__ sf, const int* __restrict__ gold,
    const __half* __restrict__ wih, const float* __restrict__ bih,
    float* __restrict__ gi_all)
{
  const int jc = blockIdx.x % 3;
  const int bb = blockIdx.x / 3;
  __shared__ float xs[T-1][256];
  const int* gr = gold + bb*T;
  for (int t=0; t<T-1; t++)
    xs[t][threadIdx.x] = sf[((size_t)bb*L_ + gr[t])*D_ + threadIdx.x];
  __syncthreads();
  const int j = jc*256 + threadIdx.x;
  const __half* wr = wih + (size_t)j*256;
  float acc[T-1];
#pragma unroll
  for (int t=0;t<T-1;t++) acc[t] = 0.f;
  for (int d0=0; d0<256; d0+=8){
    uint4 wv = *(const uint4*)(wr + d0);
    float w[8]; cvt8(wv, w);
#pragma unroll
    for (int t=0;t<T-1;t++){
      const float* xr = &xs[t][d0];
      float4 a = *(const float4*)xr;
      float4 b = *(const float4*)(xr+4);
      acc[t] += w[0]*a.x + w[1]*a.y + w[2]*a.z + w[3]*a.w
              + w[4]*b.x + w[5]*b.y + w[6]*b.z + w[7]*b.w;
    }
  }
  float bias = bih[j];
  float* go = gi_all + ((size_t)bb*32)*768 + j;
#pragma unroll
  for (int t=0;t<T-1;t++) go[(size_t)t*768] = acc[t] + bias;
}

// ---------------- K4b: GRU recurrence -> sibT[net][b][e][t]  (only gh is serial) ------
__global__ __launch_bounds__(768) void k_gru(
    const float* __restrict__ query_c, const float* __restrict__ query_p,
    const __half* __restrict__ whhH,
    const float* __restrict__ bhh_c, const float* __restrict__ bhh_p,
    const float* __restrict__ gi_all, float* __restrict__ sibT)
{
  const int net = blockIdx.x >> 6, bb = blockIdx.x & 63;
  const int T = net ? TP : TC;
  const int j = threadIdx.x;
  __shared__ float hs[256];
  __shared__ __half hsh[256];
  __shared__ float gh[768];
  const __half* wr = whhH + (size_t)net*196608 + (size_t)j*256;
  const float bias = (net ? bhh_p : bhh_c)[j];
  const float* gir = gi_all + (size_t)(net*64+bb)*32*768;
  float* sib = sibT + (size_t)(net*64+bb)*256*32;
  const float* query = net ? query_p : query_c;
  if (j < 256){ float h0 = query[j]; hs[j]=h0; hsh[j]=__float2half(h0); sib[j*32]=h0; }
  __syncthreads();
  for (int t=0; t<T-1; t++){
    float a = bias;
#pragma unroll
    for (int d0=0; d0<256; d0+=8){
      uint4 wv = *(const uint4*)(wr + d0);
      uint4 hv = *(const uint4*)(hsh + d0);
      const f16x2* wp = (const f16x2*)&wv;
      const f16x2* hp = (const f16x2*)&hv;
#pragma unroll
      for (int i2=0;i2<4;i2++) a = fdot2_(wp[i2], hp[i2], a);
    }
    gh[j] = a;
    __syncthreads();
    if (j < 256){
      const float* gi = gir + (size_t)t*768;
      float r = sigm(gi[j] + gh[j]);
      float z = sigm(gi[256+j] + gh[256+j]);
      float n = tanh_(gi[512+j] + r*gh[512+j]);
      float hn = (1.f - z)*n + z*hs[j];
      hs[j] = hn; hsh[j] = __float2half(hn);
      sib[j*32 + t + 1] = hn;
    }
    __syncthreads();
  }
}

// ---------------- K5a: q_all[b][t][k] = M[b][k][:] . sib_t[b][:] + bil_b[k] -----------
template<int T>
__global__ __launch_bounds__(256) void k_q(
    const float* __restrict__ M, const float* __restrict__ sibT,
    const float* __restrict__ bil_b, float* __restrict__ q_all)
{
  const int bb = blockIdx.x;
  const int k = threadIdx.x;
  const float* Mr = M + ((size_t)bb*256 + k)*256;
  const float* sr = sibT + ((size_t)bb*256)*32;   // [e][t], uniform -> s_load
  float acc[T];
  const float b0 = bil_b[k];
#pragma unroll
  for (int t=0;t<T;t++) acc[t] = b0;
  for (int e0=0; e0<256; e0+=4){
    float4 m4 = *(const float4*)(Mr + e0);
#pragma unroll
    for (int t=0;t<T;t++){
      acc[t] += m4.x*sr[(e0+0)*32+t] + m4.y*sr[(e0+1)*32+t]
              + m4.z*sr[(e0+2)*32+t] + m4.w*sr[(e0+3)*32+t];
    }
  }
  float* qo = q_all + ((size_t)bb*32)*256 + k;
#pragma unroll
  for (int t=0;t<T;t++) qo[(size_t)t*256] = acc[t];
}

// ---------------- K5b: qq2[net][b][e][t] = 2log2e * (q . Wq[:,e] + attn_b[e]) ---------
__global__ __launch_bounds__(256) void k_qq(
    const float* __restrict__ q_all,
    const float* __restrict__ wq_c, const float* __restrict__ wq_p,
    const float* __restrict__ ab_c, const float* __restrict__ ab_p,
    float* __restrict__ qq2)
{
  int id = blockIdx.x;
  int net, bb, t;
  if (id < 1024){ net=0; bb = id >> 4; t = id & 15; }
  else { id -= 1024; net=1; bb = id >> 5; t = id & 31; }
  const int e = threadIdx.x;
  const float* qr = q_all + (((size_t)(net*64+bb))*32 + t)*256;  // uniform -> s_load
  const float* wq = net ? wq_p : wq_c;
  float acc = (net ? ab_p : ab_c)[e];
  for (int k=0; k<256; k++)
    acc = fmaf(qr[k], wq[k*256 + e], acc);
  qq2[(((size_t)(net*64+bb))*256 + e)*32 + t] = TWO_LOG2E * acc;
}

// ---------------- K6: scores[t][b][l] = -2 * sum_d v_d * sigmoid(-2(pk+qq)) -----------
// (equals sum_d v_d tanh(pk+qq) minus the softmax-invariant constant sum_d v_d)
template<int T>
__global__ __launch_bounds__(256) void k_scores(
    const __half* __restrict__ pk, const float* __restrict__ qq2,
    const float* __restrict__ attn_v, float* __restrict__ scores)
{
  const int bb = blockIdx.x >> 3;
  const int l = (blockIdx.x & 7)*256 + threadIdx.x;
  const size_t r = (size_t)bb*L_ + l;
  const __half* pr = pk + r*512;
  const float* qr = qq2 + ((size_t)bb*256)*32;
  float acc[T];
#pragma unroll
  for (int t=0;t<T;t++) acc[t] = 0.f;
  for (int d0=0; d0<256; d0+=8){
    uint4 pv = *(const uint4*)(pr + d0);
    float x[8]; cvt8(pv, x);
#pragma unroll
    for (int jj=0;jj<8;jj++){
      const float kx = TWO_LOG2E * x[jj];
      const float* qdp = qr + (d0+jj)*32;     // uniform -> s_load
      const float v = attn_v[d0+jj];
#pragma unroll
      for (int t=0;t<T;t++){
        float exv = ex2(kx + qdp[t]);
        acc[t] = fmaf(v, rcp_(1.f + exv), acc[t]);
      }
    }
  }
#pragma unroll
  for (int t=0;t<T;t++)
    scores[((size_t)t*64 + bb)*L_ + l] = -2.f*acc[t];
}

// ---------------- K7: masked softmax over L, pick gold prob, write output -------------
__global__ __launch_bounds__(256) void k_soft(
    const float* __restrict__ scores, const int* __restrict__ mask,
    const int* __restrict__ gold_c, const int* __restrict__ gold_p,
    float* __restrict__ out)
{
  int id = blockIdx.x;
  int net, bb, t;
  if (id < 1024){ net=0; bb=id>>4; t=id&15; } else { id-=1024; net=1; bb=id>>5; t=id&31; }
  const float* sr = scores + (((size_t)net*32 + t)*64 + bb)*L_;
  const int* mr = mask + bb*L_;
  __shared__ float red[256];
  const int tid = threadIdx.x;
  float mx = -3.0e38f;
  for (int l=tid; l<L_; l+=256){
    float s = mr[l] ? sr[l] : -1e9f;
    mx = fmaxf(mx, s);
  }
  red[tid] = mx; __syncthreads();
  for (int o=128; o>0; o>>=1){ if (tid < o) red[tid] = fmaxf(red[tid], red[tid+o]); __syncthreads(); }
  mx = red[0]; __syncthreads();
  float sm = 0.f;
  for (int l=tid; l<L_; l+=256){
    float s = mr[l] ? sr[l] : -1e9f;
    sm += ex2(LOG2E*(s - mx));
  }
  red[tid] = sm; __syncthreads();
  for (int o=128; o>0; o>>=1){ if (tid < o) red[tid] += red[tid+o]; __syncthreads(); }
  if (tid == 0){
    int g = net ? gold_p[bb*TP + t] : gold_c[bb*TC + t];
    float s = mr[g] ? sr[g] : -1e9f;
    out[net ? (1024 + bb*TP + t) : (bb*TC + t)] = ex2(LOG2E*(s - mx)) / red[0];
  }
}

extern "C" void kernel_launch(void* const* d_in, const int* in_sizes, int n_in,
                              void* d_out, int out_size, void* d_ws, size_t ws_size,
                              hipStream_t stream)
{
  const float* sf      = (const float*)d_in[0];
  const int*   mask    = (const int*)d_in[1];
  const int*   gold_c  = (const int*)d_in[2];
  const int*   gold_p  = (const int*)d_in[3];
  const float* query_c = (const float*)d_in[4];
  const float* query_p = (const float*)d_in[5];
  const float* c_bw  = (const float*)d_in[6];
  const float* c_bb  = (const float*)d_in[7];
  const float* c_wq  = (const float*)d_in[8];
  const float* c_wk  = (const float*)d_in[9];
  const float* c_ab  = (const float*)d_in[10];
  const float* c_av  = (const float*)d_in[11];
  const float* c_wih = (const float*)d_in[12];
  const float* c_whh = (const float*)d_in[13];
  const float* c_bih = (const float*)d_in[14];
  const float* c_bhh = (const float*)d_in[15];
  const float* p_bw  = (const float*)d_in[16];
  const float* p_bb  = (const float*)d_in[17];
  const float* p_wq  = (const float*)d_in[18];
  const float* p_wk  = (const float*)d_in[19];
  const float* p_ab  = (const float*)d_in[20];
  const float* p_av  = (const float*)d_in[21];
  const float* p_wih = (const float*)d_in[22];
  const float* p_whh = (const float*)d_in[23];
  const float* p_bih = (const float*)d_in[24];
  const float* p_bhh = (const float*)d_in[25];
  float* out = (float*)d_out;

  char* w = (char*)d_ws;
  size_t o = 0;
  auto take = [&](size_t bytes){ char* p = w + o; o += (bytes + 255) & ~(size_t)255; return p; };
  __half* pk     = (__half*)take((size_t)131072*512*2);       // 134.2 MB
  float*  M      = (float*) take((size_t)2*64*256*256*4);     //  33.6 MB
  float*  scores = (float*) take((size_t)2*32*64*2048*4);     //  33.6 MB
  float*  q_all  = (float*) take((size_t)2*64*32*256*4);      //  16.8 MB
  float*  qq2    = (float*) take((size_t)2*64*256*32*4);      //   4.2 MB
  float*  sibT   = (float*) take((size_t)2*64*256*32*4);      //   4.2 MB
  float*  gi_all = (float*) take((size_t)2*64*32*768*4);      //  25.2 MB
  __half* wkT    = (__half*)take((size_t)512*256*2);
  __half* wihH   = (__half*)take((size_t)2*768*256*2);
  __half* whhH   = (__half*)take((size_t)2*768*256*2);
  float*  parentT= (float*) take((size_t)256*64*4);
  (void)ws_size; (void)in_sizes; (void)n_in; (void)out_size;

  k_prep<<<3648, 256, 0, stream>>>(sf, c_wk, p_wk, c_wih, p_wih, c_whh, p_whh,
                                   wkT, wihH, whhH, parentT);
  k_gemm<<<dim3(1024,4), 256, 0, stream>>>(sf, wkT, pk);
  k_M<<<512, 256, 0, stream>>>(c_bw, p_bw, parentT, M);
  k_gi<TC><<<192, 256, 0, stream>>>(sf, gold_c, wihH,          c_bih, gi_all);
  k_gi<TP><<<192, 256, 0, stream>>>(sf, gold_p, wihH + 196608, p_bih, gi_all + (size_t)64*32*768);
  k_gru<<<128, 768, 0, stream>>>(query_c, query_p, whhH, c_bhh, p_bhh, gi_all, sibT);
  k_q<TC><<<64, 256, 0, stream>>>(M,                        sibT,                      c_bb, q_all);
  k_q<TP><<<64, 256, 0, stream>>>(M + (size_t)64*256*256,   sibT + (size_t)64*256*32,  p_bb, q_all + (size_t)64*32*256);
  k_qq<<<3072, 256, 0, stream>>>(q_all, c_wq, p_wq, c_ab, p_ab, qq2);
  k_scores<TC><<<512, 256, 0, stream>>>(pk,       qq2,                       c_av, scores);
  k_scores<TP><<<512, 256, 0, stream>>>(pk + 256, qq2 + (size_t)64*256*32,   p_av, scores + (size_t)32*64*2048);
  k_soft<<<3072, 256, 0, stream>>>(scores, mask, gold_c, gold_p, out);
}

// Round 2
// 1014.307 us; speedup vs baseline: 1.3289x; 1.3289x over previous
//
#include <hip/hip_runtime.h>
#include <hip/hip_fp16.h>

#define B_ 64
#define L_ 2048
#define D_ 256
#define TC 16
#define TP 32

typedef _Float16 half8 __attribute__((ext_vector_type(8)));
typedef _Float16 f16x2 __attribute__((ext_vector_type(2)));
typedef float f32x4 __attribute__((ext_vector_type(4)));

#define LOG2E 1.4426950408889634f
#define TWO_LOG2E 2.8853900817779268f

__device__ __forceinline__ float ex2(float x){ return __builtin_amdgcn_exp2f(x); }
__device__ __forceinline__ float rcp_(float x){ return __builtin_amdgcn_rcpf(x); }
__device__ __forceinline__ float sigm(float x){ return rcp_(1.f + ex2(-LOG2E*x)); }
__device__ __forceinline__ float tanh_(float x){ return 1.f - 2.f*rcp_(1.f + ex2(TWO_LOG2E*x)); }

#if __has_builtin(__builtin_amdgcn_fdot2)
__device__ __forceinline__ float fdot2_(f16x2 a, f16x2 b, float c){ return __builtin_amdgcn_fdot2(a,b,c,false); }
#else
__device__ __forceinline__ float fdot2_(f16x2 a, f16x2 b, float c){
  return fmaf((float)a[0], (float)b[0], fmaf((float)a[1], (float)b[1], c));
}
#endif

__device__ __forceinline__ void cvt8(uint4 v, float* w){
  const __half2* h = (const __half2*)&v;
#pragma unroll
  for (int i=0;i<4;i++){ float2 f = __half22float2(h[i]); w[2*i]=f.x; w[2*i+1]=f.y; }
}

// ---------------- K1: weight prep (fp16 casts, transposed Wk, parentT) ----------------
__global__ __launch_bounds__(256) void k_prep(
    const float* __restrict__ sf,
    const float* __restrict__ wk_c, const float* __restrict__ wk_p,
    const float* __restrict__ wih_c, const float* __restrict__ wih_p,
    const float* __restrict__ whh_c, const float* __restrict__ whh_p,
    __half* __restrict__ wkT, __half* __restrict__ wihH, __half* __restrict__ whhH,
    float* __restrict__ parentT)
{
  int idx = blockIdx.x*256 + threadIdx.x;
  if (idx < 131072) {
    int c = idx >> 8, d = idx & 255;
    int net = c >> 8, e = c & 255;
    const float* w = net ? wk_p : wk_c;
    wkT[idx] = __float2half(w[d*256 + e]);           // wkT[c][d] = Wk[d][e]
  } else if (idx < 131072 + 393216) {
    int i = idx - 131072;
    const float* w = (i < 196608) ? wih_c : wih_p;
    wihH[i] = __float2half(w[(i < 196608) ? i : i - 196608]);
  } else if (idx < 131072 + 786432) {
    int i = idx - 131072 - 393216;
    const float* w = (i < 196608) ? whh_c : whh_p;
    whhH[i] = __float2half(w[(i < 196608) ? i : i - 196608]);
  } else {
    int i = idx - 131072 - 786432;                   // < 16384
    int d = i >> 6, b = i & 63;
    parentT[i] = sf[((size_t)b*L_ + (L_-2))*D_ + d];
  }
}

// ---------------- K2: proj_k GEMM  pk[r][c] = 2log2e * sum_d emb[r][d]*WkT[c][d] ------
__global__ __launch_bounds__(256) void k_gemm(
    const float* __restrict__ sf, const __half* __restrict__ wkT, __half* __restrict__ pk)
{
  __shared__ __half As[128*40];
  __shared__ __half Bs[128*40];
  const int tid = threadIdx.x;
  const int row0 = blockIdx.x * 128;
  const int col0 = blockIdx.y * 128;
  const int lane = tid & 63, wave = tid >> 6;
  const int wm = wave & 1, wn = wave >> 1;
  const int qd = lane >> 4, mr = lane & 15;
  const int rl = tid >> 1, hf = tid & 1;

  f32x4 acc[4][4];
#pragma unroll
  for (int i=0;i<4;i++)
#pragma unroll
    for (int j=0;j<4;j++) acc[i][j] = (f32x4){0.f,0.f,0.f,0.f};

  for (int kc = 0; kc < 256; kc += 32) {
    const float* asrc = sf + ((size_t)(row0+rl))*256 + kc + hf*16;
    __half* adst = As + rl*40 + hf*16;
#pragma unroll
    for (int i=0;i<4;i++){
      float4 v = ((const float4*)asrc)[i];
      __half2 h01 = __floats2half2_rn(v.x, v.y);
      __half2 h23 = __floats2half2_rn(v.z, v.w);
      uint2 u; u.x = *(const unsigned*)&h01; u.y = *(const unsigned*)&h23;
      *(uint2*)(adst + i*4) = u;
    }
    const __half* bsrc = wkT + (size_t)(col0+rl)*256 + kc + hf*16;
    __half* bdst = Bs + rl*40 + hf*16;
    *(uint4*)bdst       = *(const uint4*)bsrc;
    *(uint4*)(bdst + 8) = *(const uint4*)(bsrc + 8);
    __syncthreads();

    half8 af[4], bf[4];
#pragma unroll
    for (int tm=0;tm<4;tm++) af[tm] = *(const half8*)(As + (wm*64 + tm*16 + mr)*40 + qd*8);
#pragma unroll
    for (int tn=0;tn<4;tn++) bf[tn] = *(const half8*)(Bs + (wn*64 + tn*16 + mr)*40 + qd*8);
#pragma unroll
    for (int tm=0;tm<4;tm++)
#pragma unroll
      for (int tn=0;tn<4;tn++)
        acc[tm][tn] = __builtin_amdgcn_mfma_f32_16x16x32_f16(af[tm], bf[tn], acc[tm][tn], 0,0,0);
    __syncthreads();
  }
#pragma unroll
  for (int tm=0;tm<4;tm++)
#pragma unroll
    for (int tn=0;tn<4;tn++){
      int c = col0 + wn*64 + tn*16 + mr;
#pragma unroll
      for (int rg=0; rg<4; rg++){
        int r = row0 + wm*64 + tm*16 + qd*4 + rg;
        pk[(size_t)r*512 + c] = __float2half(TWO_LOG2E * acc[tm][tn][rg]);
      }
    }
}

// ---------------- K3: M[net][b][k][e] = sum_d parent[b][d]*bilW[k][d][e]  (fp32) ------
__global__ __launch_bounds__(256) void k_M(
    const float* __restrict__ bw_c, const float* __restrict__ bw_p,
    const float* __restrict__ parentT, float* __restrict__ M)
{
  const int net = blockIdx.x >> 8;
  const int k = blockIdx.x & 255;
  const int e = threadIdx.x;
  const float* W = (net ? bw_p : bw_c) + (size_t)k*65536 + e;
  float acc[64];
#pragma unroll
  for (int b=0;b<64;b++) acc[b] = 0.f;
  for (int d=0; d<256; d++){
    float w = W[(size_t)d*256];
    const float* pr = parentT + d*64;   // uniform -> s_load
#pragma unroll
    for (int b=0;b<64;b++) acc[b] = fmaf(pr[b], w, acc[b]);
  }
  float* Mo = M + ((size_t)net*64*256 + k)*256 + e;
#pragma unroll
  for (int b=0;b<64;b++) Mo[(size_t)b*65536] = acc[b];
}

// ---------------- K4a: gi_all[b][t][j] = x_t[b] . Wih[j] + bih[j] (all t parallel) ----
template<int T>
__global__ __launch_bounds__(256) void k_gi(
    const float* __restrict__ sf, const int* __restrict__ gold,
    const __half* __restrict__ wih, const float* __restrict__ bih,
    float* __restrict__ gi_all)
{
  const int jc = blockIdx.x % 3;
  const int bb = blockIdx.x / 3;
  __shared__ float xs[T-1][256];
  const int* gr = gold + bb*T;
  for (int t=0; t<T-1; t++)
    xs[t][threadIdx.x] = sf[((size_t)bb*L_ + gr[t])*D_ + threadIdx.x];
  __syncthreads();
  const int j = jc*256 + threadIdx.x;
  const __half* wr = wih + (size_t)j*256;
  float acc[T-1];
#pragma unroll
  for (int t=0;t<T-1;t++) acc[t] = 0.f;
  for (int d0=0; d0<256; d0+=8){
    uint4 wv = *(const uint4*)(wr + d0);
    float w[8]; cvt8(wv, w);
#pragma unroll
    for (int t=0;t<T-1;t++){
      const float* xr = &xs[t][d0];
      float4 a = *(const float4*)xr;
      float4 b = *(const float4*)(xr+4);
      acc[t] += w[0]*a.x + w[1]*a.y + w[2]*a.z + w[3]*a.w
              + w[4]*b.x + w[5]*b.y + w[6]*b.z + w[7]*b.w;
    }
  }
  float bias = bih[j];
  float* go = gi_all + ((size_t)bb*32)*768 + j;
#pragma unroll
  for (int t=0;t<T-1;t++) go[(size_t)t*768] = acc[t] + bias;
}

// ---------------- K4b: GRU recurrence -> sibT[net][b][e][t]  (only gh is serial) ------
__global__ __launch_bounds__(768) void k_gru(
    const float* __restrict__ query_c, const float* __restrict__ query_p,
    const __half* __restrict__ whhH,
    const float* __restrict__ bhh_c, const float* __restrict__ bhh_p,
    const float* __restrict__ gi_all, float* __restrict__ sibT)
{
  const int net = blockIdx.x >> 6, bb = blockIdx.x & 63;
  const int T = net ? TP : TC;
  const int j = threadIdx.x;
  __shared__ float hs[256];
  __shared__ __half hsh[256];
  __shared__ float gh[768];
  const __half* wr = whhH + (size_t)net*196608 + (size_t)j*256;
  const float bias = (net ? bhh_p : bhh_c)[j];
  const float* gir = gi_all + (size_t)(net*64+bb)*32*768;
  float* sib = sibT + (size_t)(net*64+bb)*256*32;
  const float* query = net ? query_p : query_c;
  if (j < 256){ float h0 = query[j]; hs[j]=h0; hsh[j]=__float2half(h0); sib[j*32]=h0; }
  __syncthreads();
  for (int t=0; t<T-1; t++){
    float a = bias;
#pragma unroll
    for (int d0=0; d0<256; d0+=8){
      uint4 wv = *(const uint4*)(wr + d0);
      uint4 hv = *(const uint4*)(hsh + d0);
      const f16x2* wp = (const f16x2*)&wv;
      const f16x2* hp = (const f16x2*)&hv;
#pragma unroll
      for (int i2=0;i2<4;i2++) a = fdot2_(wp[i2], hp[i2], a);
    }
    gh[j] = a;
    __syncthreads();
    if (j < 256){
      const float* gi = gir + (size_t)t*768;
      float r = sigm(gi[j] + gh[j]);
      float z = sigm(gi[256+j] + gh[256+j]);
      float n = tanh_(gi[512+j] + r*gh[512+j]);
      float hn = (1.f - z)*n + z*hs[j];
      hs[j] = hn; hsh[j] = __float2half(hn);
      sib[j*32 + t + 1] = hn;
    }
    __syncthreads();
  }
}

// ---------------- K5a: q_all[b][t][k] = M[b][k][:] . sib_t[b][:] + bil_b[k] -----------
template<int T>
__global__ __launch_bounds__(256) void k_q(
    const float* __restrict__ M, const float* __restrict__ sibT,
    const float* __restrict__ bil_b, float* __restrict__ q_all)
{
  const int bb = blockIdx.x;
  const int k = threadIdx.x;
  const float* Mr = M + ((size_t)bb*256 + k)*256;
  const float* sr = sibT + ((size_t)bb*256)*32;   // [e][t], uniform -> s_load
  float acc[T];
  const float b0 = bil_b[k];
#pragma unroll
  for (int t=0;t<T;t++) acc[t] = b0;
  for (int e0=0; e0<256; e0+=4){
    float4 m4 = *(const float4*)(Mr + e0);
#pragma unroll
    for (int t=0;t<T;t++){
      acc[t] += m4.x*sr[(e0+0)*32+t] + m4.y*sr[(e0+1)*32+t]
              + m4.z*sr[(e0+2)*32+t] + m4.w*sr[(e0+3)*32+t];
    }
  }
  float* qo = q_all + ((size_t)bb*32)*256 + k;
#pragma unroll
  for (int t=0;t<T;t++) qo[(size_t)t*256] = acc[t];
}

// ---------------- K5b: qq2[net][b][e][t] = 2log2e * (q . Wq[:,e] + attn_b[e]) ---------
__global__ __launch_bounds__(256) void k_qq(
    const float* __restrict__ q_all,
    const float* __restrict__ wq_c, const float* __restrict__ wq_p,
    const float* __restrict__ ab_c, const float* __restrict__ ab_p,
    float* __restrict__ qq2)
{
  int id = blockIdx.x;
  int net, bb, t;
  if (id < 1024){ net=0; bb = id >> 4; t = id & 15; }
  else { id -= 1024; net=1; bb = id >> 5; t = id & 31; }
  const int e = threadIdx.x;
  const float* qr = q_all + (((size_t)(net*64+bb))*32 + t)*256;  // uniform -> s_load
  const float* wq = net ? wq_p : wq_c;
  float acc = (net ? ab_p : ab_c)[e];
  for (int k=0; k<256; k++)
    acc = fmaf(qr[k], wq[k*256 + e], acc);
  qq2[(((size_t)(net*64+bb))*256 + e)*32 + t] = TWO_LOG2E * acc;
}

// ---------------- K6: fused scores, t-chunked. -----------------------------------------
// scores[net][t][b][l] = -2 * sum_d v_d * sigmoid(-2(pk+qq))   (softmax-shifted tanh)
// grid: (b=64, lchunk=8, tchunk=6); tchunk 0..1 -> claim t0={0,8}; 2..5 -> prem t0={0,8,16,24}
__global__ __launch_bounds__(256) void k_scores2(
    const __half* __restrict__ pk, const float* __restrict__ qq2,
    const float* __restrict__ av_c, const float* __restrict__ av_p,
    float* __restrict__ scores)
{
  const int bb = blockIdx.x;
  const int l  = blockIdx.y*256 + threadIdx.x;
  const int tc = blockIdx.z;
  const int net = (tc >= 2) ? 1 : 0;
  const int t0 = net ? (tc-2)*8 : tc*8;
  const __half* pr = pk + ((size_t)bb*L_ + l)*512 + net*256;
  const float* qr = qq2 + ((size_t)(net*64+bb))*256*32 + t0;    // + d*32
  const float* av = net ? av_p : av_c;

  float acc[8];
#pragma unroll
  for (int t=0;t<8;t++) acc[t] = 0.f;

  for (int d0=0; d0<256; d0+=8){
    uint4 pv = *(const uint4*)(pr + d0);
    float x[8]; cvt8(pv, x);
#pragma unroll
    for (int jj=0;jj<8;jj++){
      const int d = d0 + jj;
      float4 qa = *(const float4*)(qr + d*32);       // uniform -> scalar path
      float4 qb = *(const float4*)(qr + d*32 + 4);
      const float v = av[d];
      const float q[8] = {qa.x,qa.y,qa.z,qa.w,qb.x,qb.y,qb.z,qb.w};
#pragma unroll
      for (int t=0;t<8;t++)
        acc[t] = fmaf(v, rcp_(1.f + ex2(x[jj] + q[t])), acc[t]);
    }
  }
  float* so = scores + (((size_t)net*32 + t0)*64 + bb)*L_ + l;
#pragma unroll
  for (int t=0;t<8;t++)
    so[(size_t)t*64*L_] = -2.f*acc[t];
}

// ---------------- K7: masked softmax over L, pick gold prob, write output -------------
__global__ __launch_bounds__(256) void k_soft(
    const float* __restrict__ scores, const int* __restrict__ mask,
    const int* __restrict__ gold_c, const int* __restrict__ gold_p,
    float* __restrict__ out)
{
  int id = blockIdx.x;
  int net, bb, t;
  if (id < 1024){ net=0; bb=id>>4; t=id&15; } else { id-=1024; net=1; bb=id>>5; t=id&31; }
  const float* sr = scores + (((size_t)net*32 + t)*64 + bb)*L_;
  const int* mr = mask + bb*L_;
  __shared__ float red[256];
  const int tid = threadIdx.x;
  float mx = -3.0e38f;
  for (int l=tid; l<L_; l+=256){
    float s = mr[l] ? sr[l] : -1e9f;
    mx = fmaxf(mx, s);
  }
  red[tid] = mx; __syncthreads();
  for (int o=128; o>0; o>>=1){ if (tid < o) red[tid] = fmaxf(red[tid], red[tid+o]); __syncthreads(); }
  mx = red[0]; __syncthreads();
  float sm = 0.f;
  for (int l=tid; l<L_; l+=256){
    float s = mr[l] ? sr[l] : -1e9f;
    sm += ex2(LOG2E*(s - mx));
  }
  red[tid] = sm; __syncthreads();
  for (int o=128; o>0; o>>=1){ if (tid < o) red[tid] += red[tid+o]; __syncthreads(); }
  if (tid == 0){
    int g = net ? gold_p[bb*TP + t] : gold_c[bb*TC + t];
    float s = mr[g] ? sr[g] : -1e9f;
    out[net ? (1024 + bb*TP + t) : (bb*TC + t)] = ex2(LOG2E*(s - mx)) / red[0];
  }
}

extern "C" void kernel_launch(void* const* d_in, const int* in_sizes, int n_in,
                              void* d_out, int out_size, void* d_ws, size_t ws_size,
                              hipStream_t stream)
{
  const float* sf      = (const float*)d_in[0];
  const int*   mask    = (const int*)d_in[1];
  const int*   gold_c  = (const int*)d_in[2];
  const int*   gold_p  = (const int*)d_in[3];
  const float* query_c = (const float*)d_in[4];
  const float* query_p = (const float*)d_in[5];
  const float* c_bw  = (const float*)d_in[6];
  const float* c_bb  = (const float*)d_in[7];
  const float* c_wq  = (const float*)d_in[8];
  const float* c_wk  = (const float*)d_in[9];
  const float* c_ab  = (const float*)d_in[10];
  const float* c_av  = (const float*)d_in[11];
  const float* c_wih = (const float*)d_in[12];
  const float* c_whh = (const float*)d_in[13];
  const float* c_bih = (const float*)d_in[14];
  const float* c_bhh = (const float*)d_in[15];
  const float* p_bw  = (const float*)d_in[16];
  const float* p_bb  = (const float*)d_in[17];
  const float* p_wq  = (const float*)d_in[18];
  const float* p_wk  = (const float*)d_in[19];
  const float* p_ab  = (const float*)d_in[20];
  const float* p_av  = (const float*)d_in[21];
  const float* p_wih = (const float*)d_in[22];
  const float* p_whh = (const float*)d_in[23];
  const float* p_bih = (const float*)d_in[24];
  const float* p_bhh = (const float*)d_in[25];
  float* out = (float*)d_out;

  char* w = (char*)d_ws;
  size_t o = 0;
  auto take = [&](size_t bytes){ char* p = w + o; o += (bytes + 255) & ~(size_t)255; return p; };
  __half* pk     = (__half*)take((size_t)131072*512*2);       // 134.2 MB
  float*  M      = (float*) take((size_t)2*64*256*256*4);     //  33.6 MB
  float*  scores = (float*) take((size_t)2*32*64*2048*4);     //  33.6 MB
  float*  q_all  = (float*) take((size_t)2*64*32*256*4);      //  16.8 MB
  float*  qq2    = (float*) take((size_t)2*64*256*32*4);      //   4.2 MB
  float*  sibT   = (float*) take((size_t)2*64*256*32*4);      //   4.2 MB
  float*  gi_all = (float*) take((size_t)2*64*32*768*4);      //  25.2 MB
  __half* wkT    = (__half*)take((size_t)512*256*2);
  __half* wihH   = (__half*)take((size_t)2*768*256*2);
  __half* whhH   = (__half*)take((size_t)2*768*256*2);
  float*  parentT= (float*) take((size_t)256*64*4);
  (void)ws_size; (void)in_sizes; (void)n_in; (void)out_size;

  k_prep<<<3648, 256, 0, stream>>>(sf, c_wk, p_wk, c_wih, p_wih, c_whh, p_whh,
                                   wkT, wihH, whhH, parentT);
  k_gemm<<<dim3(1024,4), 256, 0, stream>>>(sf, wkT, pk);
  k_M<<<512, 256, 0, stream>>>(c_bw, p_bw, parentT, M);
  k_gi<TC><<<192, 256, 0, stream>>>(sf, gold_c, wihH,          c_bih, gi_all);
  k_gi<TP><<<192, 256, 0, stream>>>(sf, gold_p, wihH + 196608, p_bih, gi_all + (size_t)64*32*768);
  k_gru<<<128, 768, 0, stream>>>(query_c, query_p, whhH, c_bhh, p_bhh, gi_all, sibT);
  k_q<TC><<<64, 256, 0, stream>>>(M,                        sibT,                      c_bb, q_all);
  k_q<TP><<<64, 256, 0, stream>>>(M + (size_t)64*256*256,   sibT + (size_t)64*256*32,  p_bb, q_all + (size_t)64*32*256);
  k_qq<<<3072, 256, 0, stream>>>(q_all, c_wq, p_wq, c_ab, p_ab, qq2);
  k_scores2<<<dim3(64,8,6), 256, 0, stream>>>(pk, qq2, c_av, p_av, scores);
  k_soft<<<3072, 256, 0, stream>>>(scores, mask, gold_c, gold_p, out);
}

// Round 3
// 922.115 us; speedup vs baseline: 1.4618x; 1.1000x over previous
//
#include <hip/hip_runtime.h>
#include <hip/hip_fp16.h>

#define B_ 64
#define L_ 2048
#define D_ 256
#define TC 16
#define TP 32

typedef _Float16 half8 __attribute__((ext_vector_type(8)));
typedef _Float16 f16x2 __attribute__((ext_vector_type(2)));
typedef float f32x4 __attribute__((ext_vector_type(4)));

#define LOG2E 1.4426950408889634f
#define TWO_LOG2E 2.8853900817779268f

__device__ __forceinline__ float ex2(float x){ return __builtin_amdgcn_exp2f(x); }
__device__ __forceinline__ float rcp_(float x){ return __builtin_amdgcn_rcpf(x); }
__device__ __forceinline__ float sigm(float x){ return rcp_(1.f + ex2(-LOG2E*x)); }
__device__ __forceinline__ float tanh_(float x){ return 1.f - 2.f*rcp_(1.f + ex2(TWO_LOG2E*x)); }

#if __has_builtin(__builtin_amdgcn_fdot2)
__device__ __forceinline__ float fdot2_(f16x2 a, f16x2 b, float c){ return __builtin_amdgcn_fdot2(a,b,c,false); }
#else
__device__ __forceinline__ float fdot2_(f16x2 a, f16x2 b, float c){
  return fmaf((float)a[0], (float)b[0], fmaf((float)a[1], (float)b[1], c));
}
#endif

__device__ __forceinline__ void cvt8(uint4 v, float* w){
  const __half2* h = (const __half2*)&v;
#pragma unroll
  for (int i=0;i<4;i++){ float2 f = __half22float2(h[i]); w[2*i]=f.x; w[2*i+1]=f.y; }
}

// ---------------- K1: weight prep (fp16 casts, transposed Wk, parentT) ----------------
__global__ __launch_bounds__(256) void k_prep(
    const float* __restrict__ sf,
    const float* __restrict__ wk_c, const float* __restrict__ wk_p,
    const float* __restrict__ wih_c, const float* __restrict__ wih_p,
    const float* __restrict__ whh_c, const float* __restrict__ whh_p,
    __half* __restrict__ wkT, __half* __restrict__ wihH, __half* __restrict__ whhH,
    float* __restrict__ parentT)
{
  int idx = blockIdx.x*256 + threadIdx.x;
  if (idx < 131072) {
    int c = idx >> 8, d = idx & 255;
    int net = c >> 8, e = c & 255;
    const float* w = net ? wk_p : wk_c;
    wkT[idx] = __float2half(w[d*256 + e]);           // wkT[c][d] = Wk[d][e]
  } else if (idx < 131072 + 393216) {
    int i = idx - 131072;
    const float* w = (i < 196608) ? wih_c : wih_p;
    wihH[i] = __float2half(w[(i < 196608) ? i : i - 196608]);
  } else if (idx < 131072 + 786432) {
    int i = idx - 131072 - 393216;
    const float* w = (i < 196608) ? whh_c : whh_p;
    whhH[i] = __float2half(w[(i < 196608) ? i : i - 196608]);
  } else {
    int i = idx - 131072 - 786432;                   // < 16384
    int d = i >> 6, b = i & 63;
    parentT[i] = sf[((size_t)b*L_ + (L_-2))*D_ + d];
  }
}

// ---------------- K2: proj_k GEMM -> E[r][c] = exp(2*pk) as clamped fp16 --------------
// grid (4 cols, 1024 rows): col-siblings of a row-block co-run -> sf HBM-read once.
__global__ __launch_bounds__(256) void k_gemm(
    const float* __restrict__ sf, const __half* __restrict__ wkT, __half* __restrict__ Eo)
{
  __shared__ __half As[128*40];
  __shared__ __half Bs[128*40];
  const int tid = threadIdx.x;
  const int row0 = blockIdx.y * 128;
  const int col0 = blockIdx.x * 128;
  const int lane = tid & 63, wave = tid >> 6;
  const int wm = wave & 1, wn = wave >> 1;
  const int qd = lane >> 4, mr = lane & 15;
  const int rl = tid >> 1, hf = tid & 1;

  f32x4 acc[4][4];
#pragma unroll
  for (int i=0;i<4;i++)
#pragma unroll
    for (int j=0;j<4;j++) acc[i][j] = (f32x4){0.f,0.f,0.f,0.f};

  for (int kc = 0; kc < 256; kc += 32) {
    const float* asrc = sf + ((size_t)(row0+rl))*256 + kc + hf*16;
    __half* adst = As + rl*40 + hf*16;
#pragma unroll
    for (int i=0;i<4;i++){
      float4 v = ((const float4*)asrc)[i];
      __half2 h01 = __floats2half2_rn(v.x, v.y);
      __half2 h23 = __floats2half2_rn(v.z, v.w);
      uint2 u; u.x = *(const unsigned*)&h01; u.y = *(const unsigned*)&h23;
      *(uint2*)(adst + i*4) = u;
    }
    const __half* bsrc = wkT + (size_t)(col0+rl)*256 + kc + hf*16;
    __half* bdst = Bs + rl*40 + hf*16;
    *(uint4*)bdst       = *(const uint4*)bsrc;
    *(uint4*)(bdst + 8) = *(const uint4*)(bsrc + 8);
    __syncthreads();

    half8 af[4], bf[4];
#pragma unroll
    for (int tm=0;tm<4;tm++) af[tm] = *(const half8*)(As + (wm*64 + tm*16 + mr)*40 + qd*8);
#pragma unroll
    for (int tn=0;tn<4;tn++) bf[tn] = *(const half8*)(Bs + (wn*64 + tn*16 + mr)*40 + qd*8);
#pragma unroll
    for (int tm=0;tm<4;tm++)
#pragma unroll
      for (int tn=0;tn<4;tn++)
        acc[tm][tn] = __builtin_amdgcn_mfma_f32_16x16x32_f16(af[tm], bf[tn], acc[tm][tn], 0,0,0);
    __syncthreads();
  }
#pragma unroll
  for (int tm=0;tm<4;tm++)
#pragma unroll
    for (int tn=0;tn<4;tn++){
      int c = col0 + wn*64 + tn*16 + mr;
#pragma unroll
      for (int rg=0; rg<4; rg++){
        int r = row0 + wm*64 + tm*16 + qd*4 + rg;
        float e = ex2(TWO_LOG2E * acc[tm][tn][rg]);       // e^{2*pk}
        Eo[(size_t)r*512 + c] = __float2half(fminf(e, 65000.f));
      }
    }
}

// ---------------- K3: M[net][b][k][e] = sum_d parent[b][d]*bilW[k][d][e]  (fp32) ------
__global__ __launch_bounds__(256) void k_M(
    const float* __restrict__ bw_c, const float* __restrict__ bw_p,
    const float* __restrict__ parentT, float* __restrict__ M)
{
  const int net = blockIdx.x >> 8;
  const int k = blockIdx.x & 255;
  const int e = threadIdx.x;
  const float* W = (net ? bw_p : bw_c) + (size_t)k*65536 + e;
  float acc[64];
#pragma unroll
  for (int b=0;b<64;b++) acc[b] = 0.f;
  for (int d=0; d<256; d++){
    float w = W[(size_t)d*256];
    const float* pr = parentT + d*64;   // uniform -> s_load
#pragma unroll
    for (int b=0;b<64;b++) acc[b] = fmaf(pr[b], w, acc[b]);
  }
  float* Mo = M + ((size_t)net*64*256 + k)*256 + e;
#pragma unroll
  for (int b=0;b<64;b++) Mo[(size_t)b*65536] = acc[b];
}

// ---------------- K4a: gi_all[b][t][j] = x_t[b] . Wih[j] + bih[j] (all t parallel) ----
template<int T>
__global__ __launch_bounds__(256) void k_gi(
    const float* __restrict__ sf, const int* __restrict__ gold,
    const __half* __restrict__ wih, const float* __restrict__ bih,
    float* __restrict__ gi_all)
{
  const int jc = blockIdx.x % 3;
  const int bb = blockIdx.x / 3;
  __shared__ float xs[T-1][256];
  const int* gr = gold + bb*T;
  for (int t=0; t<T-1; t++)
    xs[t][threadIdx.x] = sf[((size_t)bb*L_ + gr[t])*D_ + threadIdx.x];
  __syncthreads();
  const int j = jc*256 + threadIdx.x;
  const __half* wr = wih + (size_t)j*256;
  float acc[T-1];
#pragma unroll
  for (int t=0;t<T-1;t++) acc[t] = 0.f;
  for (int d0=0; d0<256; d0+=8){
    uint4 wv = *(const uint4*)(wr + d0);
    float w[8]; cvt8(wv, w);
#pragma unroll
    for (int t=0;t<T-1;t++){
      const float* xr = &xs[t][d0];
      float4 a = *(const float4*)xr;
      float4 b = *(const float4*)(xr+4);
      acc[t] += w[0]*a.x + w[1]*a.y + w[2]*a.z + w[3]*a.w
              + w[4]*b.x + w[5]*b.y + w[6]*b.z + w[7]*b.w;
    }
  }
  float bias = bih[j];
  float* go = gi_all + ((size_t)bb*32)*768 + j;
#pragma unroll
  for (int t=0;t<T-1;t++) go[(size_t)t*768] = acc[t] + bias;
}

// ---------------- K4b: GRU recurrence, Whh held in VGPRs (128/thread) ------------------
__global__ __launch_bounds__(768, 3) void k_gru(
    const float* __restrict__ query_c, const float* __restrict__ query_p,
    const __half* __restrict__ whhH,
    const float* __restrict__ bhh_c, const float* __restrict__ bhh_p,
    const float* __restrict__ gi_all, float* __restrict__ sibT)
{
  const int net = blockIdx.x >> 6, bb = blockIdx.x & 63;
  const int T = net ? TP : TC;
  const int j = threadIdx.x;
  __shared__ float hs[256];
  __shared__ __half hsh[256];
  __shared__ float gh[768];
  const __half* wr = whhH + (size_t)net*196608 + (size_t)j*256;
  const float bias = (net ? bhh_p : bhh_c)[j];
  const float* gir = gi_all + (size_t)(net*64+bb)*32*768;
  float* sib = sibT + (size_t)(net*64+bb)*256*32;
  const float* query = net ? query_p : query_c;

  uint4 wreg[32];
#pragma unroll
  for (int i=0;i<32;i++) wreg[i] = ((const uint4*)wr)[i];

  if (j < 256){ float h0 = query[j]; hs[j]=h0; hsh[j]=__float2half(h0); sib[j*32]=h0; }
  __syncthreads();
  for (int t=0; t<T-1; t++){
    float a = bias;
#pragma unroll
    for (int i=0;i<32;i++){
      uint4 hv = ((const uint4*)hsh)[i];
      const f16x2* wp = (const f16x2*)&wreg[i];
      const f16x2* hp = (const f16x2*)&hv;
#pragma unroll
      for (int i2=0;i2<4;i2++) a = fdot2_(wp[i2], hp[i2], a);
    }
    gh[j] = a;
    __syncthreads();
    if (j < 256){
      const float* gi = gir + (size_t)t*768;
      float r = sigm(gi[j] + gh[j]);
      float z = sigm(gi[256+j] + gh[256+j]);
      float n = tanh_(gi[512+j] + r*gh[512+j]);
      float hn = (1.f - z)*n + z*hs[j];
      hs[j] = hn; hsh[j] = __float2half(hn);
      sib[j*32 + t + 1] = hn;
    }
    __syncthreads();
  }
}

// ---------------- K5: fused q -> qq -> Q=exp(2*qq), per (net,b,tchunk of 8) -----------
// grid (64, 6): y 0..1 -> claim t0={0,8}; y 2..5 -> prem t0={0,8,16,24}
__global__ __launch_bounds__(256) void k_qt(
    const float* __restrict__ M, const float* __restrict__ sibT,
    const float* __restrict__ bb_c, const float* __restrict__ bb_p,
    const float* __restrict__ wq_c, const float* __restrict__ wq_p,
    const float* __restrict__ ab_c, const float* __restrict__ ab_p,
    float* __restrict__ Qo)
{
  const int bb = blockIdx.x;
  const int y = blockIdx.y;
  const int net = (y >= 2) ? 1 : 0;
  const int t0 = net ? (y-2)*8 : y*8;
  const int tid = threadIdx.x;
  __shared__ float qs[256][8];

  // phase 1: q[k][ti] = bil_b[k] + sum_e M[b][k][e]*sib[e][t0+ti]
  const float* Mr = M + (((size_t)(net*64+bb))*256 + tid)*256;
  const float* sr = sibT + ((size_t)(net*64+bb))*256*32 + t0;   // uniform -> s_load
  float accq[8];
  const float b0 = (net ? bb_p : bb_c)[tid];
#pragma unroll
  for (int t=0;t<8;t++) accq[t] = b0;
  for (int e0=0; e0<256; e0+=4){
    float4 m4 = *(const float4*)(Mr + e0);
#pragma unroll
    for (int ee=0; ee<4; ee++){
      const float* sp = sr + (size_t)(e0+ee)*32;
      float4 sa = *(const float4*)sp;
      float4 sb = *(const float4*)(sp+4);
      float mv = ((const float*)&m4)[ee];
      accq[0] = fmaf(mv, sa.x, accq[0]); accq[1] = fmaf(mv, sa.y, accq[1]);
      accq[2] = fmaf(mv, sa.z, accq[2]); accq[3] = fmaf(mv, sa.w, accq[3]);
      accq[4] = fmaf(mv, sb.x, accq[4]); accq[5] = fmaf(mv, sb.y, accq[5]);
      accq[6] = fmaf(mv, sb.z, accq[6]); accq[7] = fmaf(mv, sb.w, accq[7]);
    }
  }
#pragma unroll
  for (int t=0;t<8;t++) qs[tid][t] = accq[t];
  __syncthreads();

  // phase 2: qq[e][ti] = attn_b[e] + sum_k q[k][ti]*Wq[k][e];  Q = e^{2*qq}
  const float* wq = (net ? wq_p : wq_c) + tid;
  float acc2[8];
  const float a0 = (net ? ab_p : ab_c)[tid];
#pragma unroll
  for (int t=0;t<8;t++) acc2[t] = a0;
  for (int k=0; k<256; k++){
    float w = wq[(size_t)k*256];
#pragma unroll
    for (int t=0;t<8;t++) acc2[t] = fmaf(qs[k][t], w, acc2[t]);
  }
  float* qo = Qo + (((size_t)(net*64+bb))*256 + tid)*32 + t0;
#pragma unroll
  for (int t=0;t<8;t++) qo[t] = ex2(TWO_LOG2E * acc2[t]);
}

// ---------------- K6: scores[net][t][b][l] = -2 * sum_d v_d / (1 + E*Q) ----------------
__global__ __launch_bounds__(256) void k_scores2(
    const __half* __restrict__ E, const float* __restrict__ Q,
    const float* __restrict__ av_c, const float* __restrict__ av_p,
    float* __restrict__ scores)
{
  const int bb = blockIdx.x;
  const int l  = blockIdx.y*256 + threadIdx.x;
  const int tc = blockIdx.z;
  const int net = (tc >= 2) ? 1 : 0;
  const int t0 = net ? (tc-2)*8 : tc*8;
  const __half* pr = E + ((size_t)bb*L_ + l)*512 + net*256;
  const float* qr = Q + ((size_t)(net*64+bb))*256*32 + t0;      // uniform -> s_load
  const float* av = net ? av_p : av_c;

  float acc[8];
#pragma unroll
  for (int t=0;t<8;t++) acc[t] = 0.f;

  for (int d0=0; d0<256; d0+=8){
    uint4 pv = *(const uint4*)(pr + d0);
    float x[8]; cvt8(pv, x);
#pragma unroll
    for (int jj=0;jj<8;jj++){
      const int d = d0 + jj;
      float4 qa = *(const float4*)(qr + (size_t)d*32);
      float4 qb = *(const float4*)(qr + (size_t)d*32 + 4);
      const float v = av[d];
      const float q[8] = {qa.x,qa.y,qa.z,qa.w,qb.x,qb.y,qb.z,qb.w};
#pragma unroll
      for (int t=0;t<8;t++)
        acc[t] = fmaf(v, rcp_(fmaf(x[jj], q[t], 1.f)), acc[t]);
    }
  }
  float* so = scores + (((size_t)net*32 + t0)*64 + bb)*L_ + l;
#pragma unroll
  for (int t=0;t<8;t++)
    so[(size_t)t*64*L_] = -2.f*acc[t];
}

// ---------------- K7: masked softmax over L, pick gold prob, write output -------------
__global__ __launch_bounds__(256) void k_soft(
    const float* __restrict__ scores, const int* __restrict__ mask,
    const int* __restrict__ gold_c, const int* __restrict__ gold_p,
    float* __restrict__ out)
{
  int id = blockIdx.x;
  int net, bb, t;
  if (id < 1024){ net=0; bb=id>>4; t=id&15; } else { id-=1024; net=1; bb=id>>5; t=id&31; }
  const float* sr = scores + (((size_t)net*32 + t)*64 + bb)*L_;
  const int* mr = mask + bb*L_;
  __shared__ float red[256];
  const int tid = threadIdx.x;
  float mx = -3.0e38f;
  for (int l=tid; l<L_; l+=256){
    float s = mr[l] ? sr[l] : -1e9f;
    mx = fmaxf(mx, s);
  }
  red[tid] = mx; __syncthreads();
  for (int o=128; o>0; o>>=1){ if (tid < o) red[tid] = fmaxf(red[tid], red[tid+o]); __syncthreads(); }
  mx = red[0]; __syncthreads();
  float sm = 0.f;
  for (int l=tid; l<L_; l+=256){
    float s = mr[l] ? sr[l] : -1e9f;
    sm += ex2(LOG2E*(s - mx));
  }
  red[tid] = sm; __syncthreads();
  for (int o=128; o>0; o>>=1){ if (tid < o) red[tid] += red[tid+o]; __syncthreads(); }
  if (tid == 0){
    int g = net ? gold_p[bb*TP + t] : gold_c[bb*TC + t];
    float s = mr[g] ? sr[g] : -1e9f;
    out[net ? (1024 + bb*TP + t) : (bb*TC + t)] = ex2(LOG2E*(s - mx)) / red[0];
  }
}

extern "C" void kernel_launch(void* const* d_in, const int* in_sizes, int n_in,
                              void* d_out, int out_size, void* d_ws, size_t ws_size,
                              hipStream_t stream)
{
  const float* sf      = (const float*)d_in[0];
  const int*   mask    = (const int*)d_in[1];
  const int*   gold_c  = (const int*)d_in[2];
  const int*   gold_p  = (const int*)d_in[3];
  const float* query_c = (const float*)d_in[4];
  const float* query_p = (const float*)d_in[5];
  const float* c_bw  = (const float*)d_in[6];
  const float* c_bb  = (const float*)d_in[7];
  const float* c_wq  = (const float*)d_in[8];
  const float* c_wk  = (const float*)d_in[9];
  const float* c_ab  = (const float*)d_in[10];
  const float* c_av  = (const float*)d_in[11];
  const float* c_wih = (const float*)d_in[12];
  const float* c_whh = (const float*)d_in[13];
  const float* c_bih = (const float*)d_in[14];
  const float* c_bhh = (const float*)d_in[15];
  const float* p_bw  = (const float*)d_in[16];
  const float* p_bb  = (const float*)d_in[17];
  const float* p_wq  = (const float*)d_in[18];
  const float* p_wk  = (const float*)d_in[19];
  const float* p_ab  = (const float*)d_in[20];
  const float* p_av  = (const float*)d_in[21];
  const float* p_wih = (const float*)d_in[22];
  const float* p_whh = (const float*)d_in[23];
  const float* p_bih = (const float*)d_in[24];
  const float* p_bhh = (const float*)d_in[25];
  float* out = (float*)d_out;

  char* w = (char*)d_ws;
  size_t o = 0;
  auto take = [&](size_t bytes){ char* p = w + o; o += (bytes + 255) & ~(size_t)255; return p; };
  __half* E      = (__half*)take((size_t)131072*512*2);       // 134.2 MB  e^{2 pk}
  float*  M      = (float*) take((size_t)2*64*256*256*4);     //  33.6 MB
  float*  scores = (float*) take((size_t)2*32*64*2048*4);     //  33.6 MB
  float*  Q      = (float*) take((size_t)2*64*256*32*4);      //   4.2 MB  e^{2 qq}
  float*  sibT   = (float*) take((size_t)2*64*256*32*4);      //   4.2 MB
  float*  gi_all = (float*) take((size_t)2*64*32*768*4);      //  25.2 MB
  __half* wkT    = (__half*)take((size_t)512*256*2);
  __half* wihH   = (__half*)take((size_t)2*768*256*2);
  __half* whhH   = (__half*)take((size_t)2*768*256*2);
  float*  parentT= (float*) take((size_t)256*64*4);
  (void)ws_size; (void)in_sizes; (void)n_in; (void)out_size;

  k_prep<<<3648, 256, 0, stream>>>(sf, c_wk, p_wk, c_wih, p_wih, c_whh, p_whh,
                                   wkT, wihH, whhH, parentT);
  k_gemm<<<dim3(4,1024), 256, 0, stream>>>(sf, wkT, E);
  k_M<<<512, 256, 0, stream>>>(c_bw, p_bw, parentT, M);
  k_gi<TC><<<192, 256, 0, stream>>>(sf, gold_c, wihH,          c_bih, gi_all);
  k_gi<TP><<<192, 256, 0, stream>>>(sf, gold_p, wihH + 196608, p_bih, gi_all + (size_t)64*32*768);
  k_gru<<<128, 768, 0, stream>>>(query_c, query_p, whhH, c_bhh, p_bhh, gi_all, sibT);
  k_qt<<<dim3(64,6), 256, 0, stream>>>(M, sibT, c_bb, p_bb, c_wq, p_wq, c_ab, p_ab, Q);
  k_scores2<<<dim3(64,8,6), 256, 0, stream>>>(E, Q, c_av, p_av, scores);
  k_soft<<<3072, 256, 0, stream>>>(scores, mask, gold_c, gold_p, out);
}

// Round 4
// 812.369 us; speedup vs baseline: 1.6592x; 1.1351x over previous
//
#include <hip/hip_runtime.h>
#include <hip/hip_fp16.h>

#define B_ 64
#define L_ 2048
#define D_ 256
#define TC 16
#define TP 32

typedef _Float16 half8 __attribute__((ext_vector_type(8)));
typedef _Float16 f16x2 __attribute__((ext_vector_type(2)));
typedef float f32x4 __attribute__((ext_vector_type(4)));

#define LOG2E 1.4426950408889634f
#define TWO_LOG2E 2.8853900817779268f

__device__ __forceinline__ float ex2(float x){ return __builtin_amdgcn_exp2f(x); }
__device__ __forceinline__ float rcp_(float x){ return __builtin_amdgcn_rcpf(x); }
__device__ __forceinline__ float sigm(float x){ return rcp_(1.f + ex2(-LOG2E*x)); }
__device__ __forceinline__ float tanh_(float x){ return 1.f - 2.f*rcp_(1.f + ex2(TWO_LOG2E*x)); }

#if __has_builtin(__builtin_amdgcn_fdot2)
__device__ __forceinline__ float fdot2_(f16x2 a, f16x2 b, float c){ return __builtin_amdgcn_fdot2(a,b,c,false); }
#else
__device__ __forceinline__ float fdot2_(f16x2 a, f16x2 b, float c){
  return fmaf((float)a[0], (float)b[0], fmaf((float)a[1], (float)b[1], c));
}
#endif

__device__ __forceinline__ void cvt8(uint4 v, float* w){
  const __half2* h = (const __half2*)&v;
#pragma unroll
  for (int i=0;i<4;i++){ float2 f = __half22float2(h[i]); w[2*i]=f.x; w[2*i+1]=f.y; }
}

// ---------------- K1: weight prep (fp16 casts, transposed Wk, parentT) ----------------
__global__ __launch_bounds__(256) void k_prep(
    const float* __restrict__ sf,
    const float* __restrict__ wk_c, const float* __restrict__ wk_p,
    const float* __restrict__ wih_c, const float* __restrict__ wih_p,
    const float* __restrict__ whh_c, const float* __restrict__ whh_p,
    __half* __restrict__ wkT, __half* __restrict__ wihH, __half* __restrict__ whhH,
    float* __restrict__ parentT)
{
  int idx = blockIdx.x*256 + threadIdx.x;
  if (idx < 131072) {
    int c = idx >> 8, d = idx & 255;
    int net = c >> 8, e = c & 255;
    const float* w = net ? wk_p : wk_c;
    wkT[idx] = __float2half(w[d*256 + e]);           // wkT[c][d] = Wk[d][e]
  } else if (idx < 131072 + 393216) {
    int i = idx - 131072;
    const float* w = (i < 196608) ? wih_c : wih_p;
    wihH[i] = __float2half(w[(i < 196608) ? i : i - 196608]);
  } else if (idx < 131072 + 786432) {
    int i = idx - 131072 - 393216;
    const float* w = (i < 196608) ? whh_c : whh_p;
    whhH[i] = __float2half(w[(i < 196608) ? i : i - 196608]);
  } else {
    int i = idx - 131072 - 786432;                   // < 16384
    int d = i >> 6, b = i & 63;
    parentT[i] = sf[((size_t)b*L_ + (L_-2))*D_ + d];
  }
}

// ---------------- K2: proj_k GEMM -> E[r][c] = exp(2*pk) as clamped fp16 --------------
// grid (4 cols, 1024 rows): col-siblings of a row-block co-run -> sf HBM-read once.
__global__ __launch_bounds__(256) void k_gemm(
    const float* __restrict__ sf, const __half* __restrict__ wkT, __half* __restrict__ Eo)
{
  __shared__ __half As[128*40];
  __shared__ __half Bs[128*40];
  const int tid = threadIdx.x;
  const int row0 = blockIdx.y * 128;
  const int col0 = blockIdx.x * 128;
  const int lane = tid & 63, wave = tid >> 6;
  const int wm = wave & 1, wn = wave >> 1;
  const int qd = lane >> 4, mr = lane & 15;
  const int rl = tid >> 1, hf = tid & 1;

  f32x4 acc[4][4];
#pragma unroll
  for (int i=0;i<4;i++)
#pragma unroll
    for (int j=0;j<4;j++) acc[i][j] = (f32x4){0.f,0.f,0.f,0.f};

  for (int kc = 0; kc < 256; kc += 32) {
    const float* asrc = sf + ((size_t)(row0+rl))*256 + kc + hf*16;
    __half* adst = As + rl*40 + hf*16;
#pragma unroll
    for (int i=0;i<4;i++){
      float4 v = ((const float4*)asrc)[i];
      __half2 h01 = __floats2half2_rn(v.x, v.y);
      __half2 h23 = __floats2half2_rn(v.z, v.w);
      uint2 u; u.x = *(const unsigned*)&h01; u.y = *(const unsigned*)&h23;
      *(uint2*)(adst + i*4) = u;
    }
    const __half* bsrc = wkT + (size_t)(col0+rl)*256 + kc + hf*16;
    __half* bdst = Bs + rl*40 + hf*16;
    *(uint4*)bdst       = *(const uint4*)bsrc;
    *(uint4*)(bdst + 8) = *(const uint4*)(bsrc + 8);
    __syncthreads();

    half8 af[4], bf[4];
#pragma unroll
    for (int tm=0;tm<4;tm++) af[tm] = *(const half8*)(As + (wm*64 + tm*16 + mr)*40 + qd*8);
#pragma unroll
    for (int tn=0;tn<4;tn++) bf[tn] = *(const half8*)(Bs + (wn*64 + tn*16 + mr)*40 + qd*8);
#pragma unroll
    for (int tm=0;tm<4;tm++)
#pragma unroll
      for (int tn=0;tn<4;tn++)
        acc[tm][tn] = __builtin_amdgcn_mfma_f32_16x16x32_f16(af[tm], bf[tn], acc[tm][tn], 0,0,0);
    __syncthreads();
  }
#pragma unroll
  for (int tm=0;tm<4;tm++)
#pragma unroll
    for (int tn=0;tn<4;tn++){
      int c = col0 + wn*64 + tn*16 + mr;
#pragma unroll
      for (int rg=0; rg<4; rg++){
        int r = row0 + wm*64 + tm*16 + qd*4 + rg;
        float e = ex2(TWO_LOG2E * acc[tm][tn][rg]);       // e^{2*pk}
        Eo[(size_t)r*512 + c] = __float2half(fminf(e, 65000.f));
      }
    }
}

// ---------------- K3: M[net][b][k][e] = sum_d parent[b][d]*bilW[k][d][e]  (fp32) ------
__global__ __launch_bounds__(256) void k_M(
    const float* __restrict__ bw_c, const float* __restrict__ bw_p,
    const float* __restrict__ parentT, float* __restrict__ M)
{
  const int net = blockIdx.x >> 8;
  const int k = blockIdx.x & 255;
  const int e = threadIdx.x;
  const float* W = (net ? bw_p : bw_c) + (size_t)k*65536 + e;
  float acc[64];
#pragma unroll
  for (int b=0;b<64;b++) acc[b] = 0.f;
  for (int d=0; d<256; d++){
    float w = W[(size_t)d*256];
    const float* pr = parentT + d*64;   // uniform -> s_load
#pragma unroll
    for (int b=0;b<64;b++) acc[b] = fmaf(pr[b], w, acc[b]);
  }
  float* Mo = M + ((size_t)net*64*256 + k)*256 + e;
#pragma unroll
  for (int b=0;b<64;b++) Mo[(size_t)b*65536] = acc[b];
}

// ---------------- K4a: gi_all[b][t][j] = x_t[b] . Wih[j] + bih[j] (all t parallel) ----
template<int T>
__global__ __launch_bounds__(256) void k_gi(
    const float* __restrict__ sf, const int* __restrict__ gold,
    const __half* __restrict__ wih, const float* __restrict__ bih,
    float* __restrict__ gi_all)
{
  const int jc = blockIdx.x % 3;
  const int bb = blockIdx.x / 3;
  __shared__ float xs[T-1][256];
  const int* gr = gold + bb*T;
  for (int t=0; t<T-1; t++)
    xs[t][threadIdx.x] = sf[((size_t)bb*L_ + gr[t])*D_ + threadIdx.x];
  __syncthreads();
  const int j = jc*256 + threadIdx.x;
  const __half* wr = wih + (size_t)j*256;
  float acc[T-1];
#pragma unroll
  for (int t=0;t<T-1;t++) acc[t] = 0.f;
  for (int d0=0; d0<256; d0+=8){
    uint4 wv = *(const uint4*)(wr + d0);
    float w[8]; cvt8(wv, w);
#pragma unroll
    for (int t=0;t<T-1;t++){
      const float* xr = &xs[t][d0];
      float4 a = *(const float4*)xr;
      float4 b = *(const float4*)(xr+4);
      acc[t] += w[0]*a.x + w[1]*a.y + w[2]*a.z + w[3]*a.w
              + w[4]*b.x + w[5]*b.y + w[6]*b.z + w[7]*b.w;
    }
  }
  float bias = bih[j];
  float* go = gi_all + ((size_t)bb*32)*768 + j;
#pragma unroll
  for (int t=0;t<T-1;t++) go[(size_t)t*768] = acc[t] + bias;
}

// ---------------- K4b: GRU recurrence, Whh held in VGPRs (128/thread) ------------------
__global__ __launch_bounds__(768, 3) void k_gru(
    const float* __restrict__ query_c, const float* __restrict__ query_p,
    const __half* __restrict__ whhH,
    const float* __restrict__ bhh_c, const float* __restrict__ bhh_p,
    const float* __restrict__ gi_all, float* __restrict__ sibT)
{
  const int net = blockIdx.x >> 6, bb = blockIdx.x & 63;
  const int T = net ? TP : TC;
  const int j = threadIdx.x;
  __shared__ float hs[256];
  __shared__ __half hsh[256];
  __shared__ float gh[768];
  const __half* wr = whhH + (size_t)net*196608 + (size_t)j*256;
  const float bias = (net ? bhh_p : bhh_c)[j];
  const float* gir = gi_all + (size_t)(net*64+bb)*32*768;
  float* sib = sibT + (size_t)(net*64+bb)*256*32;
  const float* query = net ? query_p : query_c;

  uint4 wreg[32];
#pragma unroll
  for (int i=0;i<32;i++) wreg[i] = ((const uint4*)wr)[i];

  if (j < 256){ float h0 = query[j]; hs[j]=h0; hsh[j]=__float2half(h0); sib[j*32]=h0; }
  __syncthreads();
  for (int t=0; t<T-1; t++){
    float a = bias;
#pragma unroll
    for (int i=0;i<32;i++){
      uint4 hv = ((const uint4*)hsh)[i];
      const f16x2* wp = (const f16x2*)&wreg[i];
      const f16x2* hp = (const f16x2*)&hv;
#pragma unroll
      for (int i2=0;i2<4;i2++) a = fdot2_(wp[i2], hp[i2], a);
    }
    gh[j] = a;
    __syncthreads();
    if (j < 256){
      const float* gi = gir + (size_t)t*768;
      float r = sigm(gi[j] + gh[j]);
      float z = sigm(gi[256+j] + gh[256+j]);
      float n = tanh_(gi[512+j] + r*gh[512+j]);
      float hn = (1.f - z)*n + z*hs[j];
      hs[j] = hn; hsh[j] = __float2half(hn);
      sib[j*32 + t + 1] = hn;
    }
    __syncthreads();
  }
}

// ---------------- K5: fused q -> qq -> Q=exp(2*qq), per (net,b,tchunk of 8) -----------
// grid (64, 6): y 0..1 -> claim t0={0,8}; y 2..5 -> prem t0={0,8,16,24}
__global__ __launch_bounds__(256) void k_qt(
    const float* __restrict__ M, const float* __restrict__ sibT,
    const float* __restrict__ bb_c, const float* __restrict__ bb_p,
    const float* __restrict__ wq_c, const float* __restrict__ wq_p,
    const float* __restrict__ ab_c, const float* __restrict__ ab_p,
    float* __restrict__ Qo)
{
  const int bb = blockIdx.x;
  const int y = blockIdx.y;
  const int net = (y >= 2) ? 1 : 0;
  const int t0 = net ? (y-2)*8 : y*8;
  const int tid = threadIdx.x;
  __shared__ float qs[256][8];

  // phase 1: q[k][ti] = bil_b[k] + sum_e M[b][k][e]*sib[e][t0+ti]
  const float* Mr = M + (((size_t)(net*64+bb))*256 + tid)*256;
  const float* sr = sibT + ((size_t)(net*64+bb))*256*32 + t0;   // uniform -> s_load
  float accq[8];
  const float b0 = (net ? bb_p : bb_c)[tid];
#pragma unroll
  for (int t=0;t<8;t++) accq[t] = b0;
  for (int e0=0; e0<256; e0+=4){
    float4 m4 = *(const float4*)(Mr + e0);
#pragma unroll
    for (int ee=0; ee<4; ee++){
      const float* sp = sr + (size_t)(e0+ee)*32;
      float4 sa = *(const float4*)sp;
      float4 sb = *(const float4*)(sp+4);
      float mv = ((const float*)&m4)[ee];
      accq[0] = fmaf(mv, sa.x, accq[0]); accq[1] = fmaf(mv, sa.y, accq[1]);
      accq[2] = fmaf(mv, sa.z, accq[2]); accq[3] = fmaf(mv, sa.w, accq[3]);
      accq[4] = fmaf(mv, sb.x, accq[4]); accq[5] = fmaf(mv, sb.y, accq[5]);
      accq[6] = fmaf(mv, sb.z, accq[6]); accq[7] = fmaf(mv, sb.w, accq[7]);
    }
  }
#pragma unroll
  for (int t=0;t<8;t++) qs[tid][t] = accq[t];
  __syncthreads();

  // phase 2: qq[e][ti] = attn_b[e] + sum_k q[k][ti]*Wq[k][e];  Q = e^{2*qq}
  const float* wq = (net ? wq_p : wq_c) + tid;
  float acc2[8];
  const float a0 = (net ? ab_p : ab_c)[tid];
#pragma unroll
  for (int t=0;t<8;t++) acc2[t] = a0;
  for (int k=0; k<256; k++){
    float w = wq[(size_t)k*256];
#pragma unroll
    for (int t=0;t<8;t++) acc2[t] = fmaf(qs[k][t], w, acc2[t]);
  }
  float* qo = Qo + (((size_t)(net*64+bb))*256 + tid)*32 + t0;
#pragma unroll
  for (int t=0;t<8;t++) qo[t] = ex2(TWO_LOG2E * acc2[t]);
}

// ---------------- K6: fused scores + exp + partial softmax sums ------------------------
// grid (b=64, lc=8, nc=3): nc=0 claim t0=0; nc=1 prem t0=0; nc=2 prem t0=16. 16 t/block.
// partials[nc][b][lc][t] = sum_{l in chunk} exp(score);  gold_e[net][b][t] = exp(score at gold l)
__global__ __launch_bounds__(256) void k_fused(
    const __half* __restrict__ E, const float* __restrict__ Q,
    const float* __restrict__ av_c, const float* __restrict__ av_p,
    const int* __restrict__ mask,
    const int* __restrict__ gold_c, const int* __restrict__ gold_p,
    float* __restrict__ partials, float* __restrict__ gold_e)
{
  const int bb = blockIdx.x;
  const int lc = blockIdx.y;
  const int nc = blockIdx.z;
  const int net = nc ? 1 : 0;
  const int t0 = (nc == 2) ? 16 : 0;
  const int l  = lc*256 + threadIdx.x;
  const __half* pr = E + ((size_t)bb*L_ + l)*512 + net*256;
  const float* qr = Q + ((size_t)(net*64+bb))*256*32 + t0;      // uniform -> s_load
  const float* av = net ? av_p : av_c;

  float acc[16];
#pragma unroll
  for (int t=0;t<16;t++) acc[t] = 0.f;

  for (int d0=0; d0<256; d0+=8){
    uint4 pv = *(const uint4*)(pr + d0);
    float x[8]; cvt8(pv, x);
#pragma unroll
    for (int jj=0;jj<8;jj++){
      const int d = d0 + jj;
      float4 qa = *(const float4*)(qr + (size_t)d*32);
      float4 qb = *(const float4*)(qr + (size_t)d*32 + 4);
      float4 qc = *(const float4*)(qr + (size_t)d*32 + 8);
      float4 qd4= *(const float4*)(qr + (size_t)d*32 + 12);
      const float v = av[d];
      const float q[16] = {qa.x,qa.y,qa.z,qa.w,qb.x,qb.y,qb.z,qb.w,
                           qc.x,qc.y,qc.z,qc.w,qd4.x,qd4.y,qd4.z,qd4.w};
#pragma unroll
      for (int t=0;t<16;t++)
        acc[t] = fmaf(v, rcp_(fmaf(x[jj], q[t], 1.f)), acc[t]);
    }
  }

  // exp(score) = exp(-2*acc); masked -> 0 contribution (matches exp(NEG) ~ 0)
  const int m = mask[bb*L_ + l];
  float ex[16];
#pragma unroll
  for (int t=0;t<16;t++) ex[t] = m ? ex2(-TWO_LOG2E * acc[t]) : 0.f;

  // capture gold numerator (exactly one thread per (t) matches across the lc-grid)
  const int* g = net ? (gold_p + bb*TP + t0) : (gold_c + bb*TC);
#pragma unroll
  for (int t=0;t<16;t++)
    if (l == g[t]) gold_e[net*2048 + bb*32 + t0 + t] = ex[t];

  // wave reduction (64 lanes)
#pragma unroll
  for (int off=1; off<64; off<<=1)
#pragma unroll
    for (int t=0;t<16;t++) ex[t] += __shfl_xor(ex[t], off, 64);

  __shared__ float red4[4][16];
  const int lane = threadIdx.x & 63, wave = threadIdx.x >> 6;
  if (lane == 0)
#pragma unroll
    for (int t=0;t<16;t++) red4[wave][t] = ex[t];
  __syncthreads();
  if (threadIdx.x < 16){
    float s = red4[0][threadIdx.x] + red4[1][threadIdx.x]
            + red4[2][threadIdx.x] + red4[3][threadIdx.x];
    partials[(((size_t)nc*64 + bb)*8 + lc)*16 + threadIdx.x] = s;
  }
}

// ---------------- K7: finalize -> out = gold_e / sum(partials) -------------------------
__global__ __launch_bounds__(256) void k_fin(
    const float* __restrict__ partials, const float* __restrict__ gold_e,
    float* __restrict__ out)
{
  int id = blockIdx.x*256 + threadIdx.x;
  if (id >= 3072) return;
  int net, bb, t, nc, tt;
  if (id < 1024){ net=0; bb=id>>4; t=id&15; nc=0; tt=t; }
  else { int i=id-1024; net=1; bb=i>>5; t=i&31; nc=1+(t>>4); tt=t&15; }
  const float* pr = partials + (((size_t)nc*64 + bb)*8)*16 + tt;
  float s = 0.f;
#pragma unroll
  for (int lcx=0; lcx<8; lcx++) s += pr[lcx*16];
  out[net ? (1024 + bb*TP + t) : (bb*TC + t)] = gold_e[net*2048 + bb*32 + t] / s;
}

extern "C" void kernel_launch(void* const* d_in, const int* in_sizes, int n_in,
                              void* d_out, int out_size, void* d_ws, size_t ws_size,
                              hipStream_t stream)
{
  const float* sf      = (const float*)d_in[0];
  const int*   mask    = (const int*)d_in[1];
  const int*   gold_c  = (const int*)d_in[2];
  const int*   gold_p  = (const int*)d_in[3];
  const float* query_c = (const float*)d_in[4];
  const float* query_p = (const float*)d_in[5];
  const float* c_bw  = (const float*)d_in[6];
  const float* c_bb  = (const float*)d_in[7];
  const float* c_wq  = (const float*)d_in[8];
  const float* c_wk  = (const float*)d_in[9];
  const float* c_ab  = (const float*)d_in[10];
  const float* c_av  = (const float*)d_in[11];
  const float* c_wih = (const float*)d_in[12];
  const float* c_whh = (const float*)d_in[13];
  const float* c_bih = (const float*)d_in[14];
  const float* c_bhh = (const float*)d_in[15];
  const float* p_bw  = (const float*)d_in[16];
  const float* p_bb  = (const float*)d_in[17];
  const float* p_wq  = (const float*)d_in[18];
  const float* p_wk  = (const float*)d_in[19];
  const float* p_ab  = (const float*)d_in[20];
  const float* p_av  = (const float*)d_in[21];
  const float* p_wih = (const float*)d_in[22];
  const float* p_whh = (const float*)d_in[23];
  const float* p_bih = (const float*)d_in[24];
  const float* p_bhh = (const float*)d_in[25];
  float* out = (float*)d_out;

  char* w = (char*)d_ws;
  size_t o = 0;
  auto take = [&](size_t bytes){ char* p = w + o; o += (bytes + 255) & ~(size_t)255; return p; };
  __half* E      = (__half*)take((size_t)131072*512*2);       // 134.2 MB  e^{2 pk}
  float*  M      = (float*) take((size_t)2*64*256*256*4);     //  33.6 MB
  float*  Q      = (float*) take((size_t)2*64*256*32*4);      //   4.2 MB  e^{2 qq}
  float*  sibT   = (float*) take((size_t)2*64*256*32*4);      //   4.2 MB
  float*  gi_all = (float*) take((size_t)2*64*32*768*4);      //  25.2 MB
  float*  partials=(float*) take((size_t)3*64*8*16*4);        // 196 KB
  float*  gold_e = (float*) take((size_t)2*64*32*4);          //  16 KB
  __half* wkT    = (__half*)take((size_t)512*256*2);
  __half* wihH   = (__half*)take((size_t)2*768*256*2);
  __half* whhH   = (__half*)take((size_t)2*768*256*2);
  float*  parentT= (float*) take((size_t)256*64*4);
  (void)ws_size; (void)in_sizes; (void)n_in; (void)out_size;

  k_prep<<<3648, 256, 0, stream>>>(sf, c_wk, p_wk, c_wih, p_wih, c_whh, p_whh,
                                   wkT, wihH, whhH, parentT);
  k_gemm<<<dim3(4,1024), 256, 0, stream>>>(sf, wkT, E);
  k_M<<<512, 256, 0, stream>>>(c_bw, p_bw, parentT, M);
  k_gi<TC><<<192, 256, 0, stream>>>(sf, gold_c, wihH,          c_bih, gi_all);
  k_gi<TP><<<192, 256, 0, stream>>>(sf, gold_p, wihH + 196608, p_bih, gi_all + (size_t)64*32*768);
  k_gru<<<128, 768, 0, stream>>>(query_c, query_p, whhH, c_bhh, p_bhh, gi_all, sibT);
  k_qt<<<dim3(64,6), 256, 0, stream>>>(M, sibT, c_bb, p_bb, c_wq, p_wq, c_ab, p_ab, Q);
  k_fused<<<dim3(64,8,3), 256, 0, stream>>>(E, Q, c_av, p_av, mask, gold_c, gold_p,
                                            partials, gold_e);
  k_fin<<<12, 256, 0, stream>>>(partials, gold_e, out);
}